// Round 1
// baseline (329.824 us; speedup 1.0000x reference)
//
#include <hip/hip_runtime.h>
#include <math.h>

#define HID 128
#define BQ (256*256)          // low-res pixels per batch image
#define NPIX_LR (8*BQ)        // 524288
#define OW 512
#define NPIX_HR (8*OW*OW)     // 2097152
#define OUT_OFF_DX 6291456    // 2097152*3
#define OUT_OFF_VAR 6291472   // + 16

// ---------------- Kernel A: low-res MLP (coords -> 2->128->128->3), color affine ----------------
__global__ __launch_bounds__(256, 2) void inr_mlp_lr(
    const float* __restrict__ x,
    const int* __restrict__ sample_idx,
    const float* __restrict__ shift_vectors,
    const float* __restrict__ rotation_angle,
    const float* __restrict__ color_w,
    const float* __restrict__ color_b,
    const float* __restrict__ w1, const float* __restrict__ b1,
    const float* __restrict__ w2, const float* __restrict__ b2,
    const float* __restrict__ w3, const float* __restrict__ b3,
    float* __restrict__ lr)
{
    __shared__ float sW2[HID*HID];   // 64 KB
    __shared__ float sW1[2*HID];
    __shared__ float sB1[HID];
    __shared__ float sB2[HID];
    __shared__ float sW3[HID*3];

    // stage weights to LDS (coalesced float4 for w2)
    {
        const float4* src = (const float4*)w2;
        float4* dst = (float4*)sW2;
        for (int i = threadIdx.x; i < HID*HID/4; i += 256) dst[i] = src[i];
        for (int i = threadIdx.x; i < 2*HID; i += 256) sW1[i] = w1[i];
        for (int i = threadIdx.x; i < HID; i += 256) { sB1[i] = b1[i]; sB2[i] = b2[i]; }
        for (int i = threadIdx.x; i < 3*HID; i += 256) sW3[i] = w3[i];
    }

    int p = blockIdx.x * 256 + threadIdx.x;   // 0 .. 524287
    int b = p >> 16;                          // 65536 px per image
    int si = sample_idx[b];
    float ang = rotation_angle[si];
    float sn, cs;
    sincosf(ang, &sn, &cs);
    float shx = shift_vectors[2*si+0];
    float shy = shift_vectors[2*si+1];
    float2 xv = ((const float2*)x)[p];
    // coords = x @ R^T + shift ; R[0,:]=[c,-s], R[1,:]=[s,c]
    float cx = fmaf(cs, xv.x, -sn*xv.y) + shx;
    float cy = fmaf(sn, xv.x,  cs*xv.y) + shy;

    __syncthreads();

    // layer 1: 2 -> 128, h1 kept in VGPRs (fully static indexing)
    float h1[HID];
    #pragma unroll
    for (int k = 0; k < HID; k += 4) {
        float4 wa = *(const float4*)&sW1[k];
        float4 wb = *(const float4*)&sW1[HID + k];
        float4 bb = *(const float4*)&sB1[k];
        h1[k+0] = fmaxf(0.f, fmaf(cx, wa.x, fmaf(cy, wb.x, bb.x)));
        h1[k+1] = fmaxf(0.f, fmaf(cx, wa.y, fmaf(cy, wb.y, bb.y)));
        h1[k+2] = fmaxf(0.f, fmaf(cx, wa.z, fmaf(cy, wb.z, bb.z)));
        h1[k+3] = fmaxf(0.f, fmaf(cx, wa.w, fmaf(cy, wb.w, bb.w)));
    }

    float o0 = b3[0], o1 = b3[1], o2 = b3[2];

    // layer 2 (128x128) fused with layer 3 (128->3), 16 outputs at a time
    for (int j0 = 0; j0 < HID; j0 += 16) {
        float t[16];
        #pragma unroll
        for (int u = 0; u < 16; u += 4) {
            float4 bv = *(const float4*)&sB2[j0 + u];
            t[u+0]=bv.x; t[u+1]=bv.y; t[u+2]=bv.z; t[u+3]=bv.w;
        }
        #pragma unroll
        for (int k = 0; k < HID; k++) {
            float hk = h1[k];
            #pragma unroll
            for (int u = 0; u < 16; u += 4) {
                float4 wv = *(const float4*)&sW2[k*HID + j0 + u];  // broadcast read
                t[u+0] = fmaf(hk, wv.x, t[u+0]);
                t[u+1] = fmaf(hk, wv.y, t[u+1]);
                t[u+2] = fmaf(hk, wv.z, t[u+2]);
                t[u+3] = fmaf(hk, wv.w, t[u+3]);
            }
        }
        #pragma unroll
        for (int u = 0; u < 16; u++) {
            float a = fmaxf(0.f, t[u]);
            o0 = fmaf(a, sW3[(j0+u)*3+0], o0);
            o1 = fmaf(a, sW3[(j0+u)*3+1], o1);
            o2 = fmaf(a, sW3[(j0+u)*3+2], o2);
        }
    }

    if (si != 0) {
        o0 = fmaf(o0, color_w[si*3+0], color_b[si*3+0]);
        o1 = fmaf(o1, color_w[si*3+1], color_b[si*3+1]);
        o2 = fmaf(o2, color_w[si*3+2], color_b[si*3+2]);
    }
    // SoA layout for cheap channel-wise gathers in kernel B
    lr[0*NPIX_LR + p] = o0;
    lr[1*NPIX_LR + p] = o1;
    lr[2*NPIX_LR + p] = o2;
}

// ---------------- Kernel B: 2x bilinear upsample + variance MLP (3->128->3) + dx/dy ----------------
__global__ __launch_bounds__(256) void inr_upsample_var(
    const float* __restrict__ lr,
    const int* __restrict__ sample_idx,
    const float* __restrict__ shift_vectors,
    const float* __restrict__ vw1, const float* __restrict__ vb1,
    const float* __restrict__ vw2, const float* __restrict__ vb2,
    float* __restrict__ out)
{
    int p = blockIdx.x * 256 + threadIdx.x;   // 0 .. 2097151
    int b = p >> 18;                          // 512*512 per image
    int r = p & (OW*OW - 1);
    int oy = r >> 9, ox = r & (OW - 1);

    // jax.image.resize bilinear, scale 2: sample = o/2 - 0.25, normalized edge weights
    // == clamped-index {0.25, 0.75} taps
    int my = oy >> 1; int y0, y1; float wy0, wy1;
    if (oy & 1) { y0 = my; y1 = my < 255 ? my + 1 : 255; wy0 = 0.75f; wy1 = 0.25f; }
    else        { y0 = my > 0 ? my - 1 : 0; y1 = my;     wy0 = 0.25f; wy1 = 0.75f; }
    int mx = ox >> 1; int x0, x1; float wx0, wx1;
    if (ox & 1) { x0 = mx; x1 = mx < 255 ? mx + 1 : 255; wx0 = 0.75f; wx1 = 0.25f; }
    else        { x0 = mx > 0 ? mx - 1 : 0; x1 = mx;     wx0 = 0.25f; wx1 = 0.75f; }

    int base = b * BQ;
    int i00 = base + y0*256 + x0;
    int i01 = base + y0*256 + x1;
    int i10 = base + y1*256 + x0;
    int i11 = base + y1*256 + x1;

    float o[3];
    #pragma unroll
    for (int c = 0; c < 3; c++) {
        const float* L = lr + c*NPIX_LR;
        o[c] = wy0*(wx0*L[i00] + wx1*L[i01]) + wy1*(wx0*L[i10] + wx1*L[i11]);
    }
    out[p*3+0] = o[0]; out[p*3+1] = o[1]; out[p*3+2] = o[2];

    // variance MLP: 3 -> 128 -> 3, exp
    float a0 = vb2[0], a1 = vb2[1], a2 = vb2[2];
    #pragma unroll 8
    for (int j = 0; j < HID; j++) {
        float vh = fmaf(o[0], vw1[j], fmaf(o[1], vw1[HID+j], fmaf(o[2], vw1[2*HID+j], vb1[j])));
        vh = fmaxf(0.f, vh);
        a0 = fmaf(vh, vw2[j*3+0], a0);
        a1 = fmaf(vh, vw2[j*3+1], a1);
        a2 = fmaf(vh, vw2[j*3+2], a2);
    }
    float* var = out + OUT_OFF_VAR;
    var[p*3+0] = expf(a0);
    var[p*3+1] = expf(a1);
    var[p*3+2] = expf(a2);

    // dx_list / dy_list (8 each)
    if (p < 16) {
        int i = p & 7;
        int s2 = sample_idx[i];
        out[OUT_OFF_DX + p] = shift_vectors[2*s2 + (p >> 3)];
    }
}

extern "C" void kernel_launch(void* const* d_in, const int* in_sizes, int n_in,
                              void* d_out, int out_size, void* d_ws, size_t ws_size,
                              hipStream_t stream)
{
    const float* x    = (const float*)d_in[0];
    const int*   sidx = (const int*)d_in[1];
    // d_in[2] = scale_factor (=2, hardcoded)
    const float* shv  = (const float*)d_in[3];
    const float* rot  = (const float*)d_in[4];
    const float* cw   = (const float*)d_in[5];
    const float* cb   = (const float*)d_in[6];
    const float* w1   = (const float*)d_in[7];
    const float* b1   = (const float*)d_in[8];
    const float* w2   = (const float*)d_in[9];
    const float* b2   = (const float*)d_in[10];
    const float* w3   = (const float*)d_in[11];
    const float* b3   = (const float*)d_in[12];
    const float* vw1  = (const float*)d_in[13];
    const float* vb1  = (const float*)d_in[14];
    const float* vw2  = (const float*)d_in[15];
    const float* vb2  = (const float*)d_in[16];

    float* lr = (float*)d_ws;  // 3 * 524288 floats = 6.3 MB scratch (SoA)

    inr_mlp_lr<<<NPIX_LR/256, 256, 0, stream>>>(x, sidx, shv, rot, cw, cb,
                                                w1, b1, w2, b2, w3, b3, lr);
    inr_upsample_var<<<NPIX_HR/256, 256, 0, stream>>>(lr, sidx, shv,
                                                      vw1, vb1, vw2, vb2,
                                                      (float*)d_out);
}

// Round 3
// 162.856 us; speedup vs baseline: 2.0253x; 2.0253x over previous
//
#include <hip/hip_runtime.h>
#include <math.h>

#define HID 128
#define BQ (256*256)
#define NPIX_LR (8*BQ)        // 524288
#define OW 512
#define NPIX_HR (8*OW*OW)     // 2097152
#define OUT_OFF_DX 6291456
#define OUT_OFF_VAR 6291472

// ws layout (bytes)
#define WS_BHI   0          // 32768 : w2 hi f16 frags
#define WS_BLO   32768      // 32768 : w2 lo f16 frags
#define WS_W1PK  65536      // 1024  : w1 pairs (float4 x64)
#define WS_B1PK  66560      // 512   : b1 pairs (float2 x64)
#define WS_PK0   67072      // 1024  : vw1 rows0,1 pairs
#define WS_PK1   68096      // 1024  : vw1 row2 + vb1 pairs
#define WS_PK2   69120      // 1024  : vw2 c0,c1 pairs
#define WS_PK3   70144      // 512   : vw2 c2 pairs
#define WS_LR    73728      // 6.29MB: low-res SoA

typedef _Float16 f16x8 __attribute__((ext_vector_type(8)));
typedef float    f32x4 __attribute__((ext_vector_type(4)));
typedef float    f32x2 __attribute__((ext_vector_type(2)));

union U16B { uint4 u; f16x8 h; };

static __device__ inline f32x2 pk_fma(f32x2 a, f32x2 b, f32x2 c) {
    f32x2 d;
    asm("v_pk_fma_f32 %0, %1, %2, %3" : "=v"(d) : "v"(a), "v"(b), "v"(c));
    return d;
}
static __device__ inline f32x2 pk_max0(f32x2 a) {
    f32x2 d;
    d[0] = fmaxf(a[0], 0.f);
    d[1] = fmaxf(a[1], 0.f);
    return d;
}

// ---------------- Prep: pack weights into fragment / pair layouts ----------------
__global__ void inr_prep(const float* __restrict__ w1, const float* __restrict__ b1,
                         const float* __restrict__ w2,
                         const float* __restrict__ vw1, const float* __restrict__ vb1,
                         const float* __restrict__ vw2, char* ws)
{
    int tid = blockIdx.x * 256 + threadIdx.x;
    if (tid < 8192) {
        // dword index = (((h*4+t)*4+s)*64 + lane)*4 + d
        int d = tid & 3, lane = (tid >> 2) & 63, s = (tid >> 8) & 3, t = (tid >> 10) & 3, h = tid >> 12;
        int f0  = (lane >> 4) * 8 + 2 * d + 32 * s;      // feature (k) index, low elem
        int col = (lane & 15) + 16 * t + 64 * h;
        float a0 = w2[f0 * HID + col], a1 = w2[(f0 + 1) * HID + col];
        _Float16 h0 = (_Float16)a0, h1 = (_Float16)a1;
        float r0 = a0 - (float)h0, r1 = a1 - (float)h1;
        union { _Float16 f[2]; unsigned u; } ph, pl;
        ph.f[0] = h0; ph.f[1] = h1;
        pl.f[0] = (_Float16)r0; pl.f[1] = (_Float16)r1;
        ((unsigned*)(ws + WS_BHI))[tid] = ph.u;
        ((unsigned*)(ws + WS_BLO))[tid] = pl.u;
    } else if (tid < 8256) {
        int fp = tid - 8192;  // feature pair 0..63
        float4 w; w.x = w1[2*fp]; w.y = w1[2*fp+1]; w.z = w1[HID+2*fp]; w.w = w1[HID+2*fp+1];
        ((float4*)(ws + WS_W1PK))[fp] = w;
        float2 b; b.x = b1[2*fp]; b.y = b1[2*fp+1];
        ((float2*)(ws + WS_B1PK))[fp] = b;
    } else if (tid < 8320) {
        int q = tid - 8256;   // hidden pair 0..63
        float4 p0; p0.x = vw1[2*q]; p0.y = vw1[2*q+1]; p0.z = vw1[HID+2*q]; p0.w = vw1[HID+2*q+1];
        float4 p1; p1.x = vw1[2*HID+2*q]; p1.y = vw1[2*HID+2*q+1]; p1.z = vb1[2*q]; p1.w = vb1[2*q+1];
        float4 p2; p2.x = vw2[2*q*3+0]; p2.y = vw2[(2*q+1)*3+0]; p2.z = vw2[2*q*3+1]; p2.w = vw2[(2*q+1)*3+1];
        float2 p3; p3.x = vw2[2*q*3+2]; p3.y = vw2[(2*q+1)*3+2];
        ((float4*)(ws + WS_PK0))[q] = p0;
        ((float4*)(ws + WS_PK1))[q] = p1;
        ((float4*)(ws + WS_PK2))[q] = p2;
        ((float2*)(ws + WS_PK3))[q] = p3;
    }
}

// ---------------- Kernel A: MFMA split-f16 MLP over low-res pixels ----------------
// Block = 4 waves. wave = (pset | hf<<1): pset = pixel subset (16 px), hf = col half (64 cols).
// Each block-iter handles 32 px; block covers 1024 contiguous px over 32 iters.
__global__ __launch_bounds__(256, 2) void inr_mlp_mfma(
    const float* __restrict__ x, const int* __restrict__ sidx,
    const float* __restrict__ shv, const float* __restrict__ rot,
    const float* __restrict__ cw, const float* __restrict__ cb,
    const float* __restrict__ b2g, const float* __restrict__ w3g,
    const float* __restrict__ b3g, const char* __restrict__ ws_ro, float* __restrict__ lr)
{
    __shared__ float4 sW1[64];
    __shared__ float2 sB1[64];
    __shared__ float  sX[2][16][3];

    int tid = threadIdx.x;
    if (tid < 64) {
        sW1[tid] = ((const float4*)(ws_ro + WS_W1PK))[tid];
        sB1[tid] = ((const float2*)(ws_ro + WS_B1PK))[tid];
    }
    int l = tid & 63, wv = tid >> 6;
    int li = l & 15, g = l >> 4;
    int pset = wv & 1, hf = wv >> 1;

    // stationary W2 fragments (hi + lo) for this wave's 64-col half
    const uint4* Bhi = (const uint4*)(ws_ro + WS_BHI);
    const uint4* Blo = (const uint4*)(ws_ro + WS_BLO);
    f16x8 Bh[4][4], Bl[4][4];
    #pragma unroll
    for (int t = 0; t < 4; t++)
        #pragma unroll
        for (int s = 0; s < 4; s++) {
            int idx = ((hf * 4 + t) * 4 + s) * 64 + l;
            U16B uh; uh.u = Bhi[idx]; Bh[t][s] = uh.h;
            U16B ul; ul.u = Blo[idx]; Bl[t][s] = ul.h;
        }
    float b2v[4], w3v[4][3];
    #pragma unroll
    for (int t = 0; t < 4; t++) {
        int col = li + 16 * t + 64 * hf;
        b2v[t] = b2g[col];
        w3v[t][0] = w3g[col * 3 + 0];
        w3v[t][1] = w3g[col * 3 + 1];
        w3v[t][2] = w3g[col * 3 + 2];
    }
    __syncthreads();

    for (int it = 0; it < 32; it++) {
        int p0 = blockIdx.x * 1024 + it * 32 + pset * 16;  // this wave's 16 px
        int img = p0 >> 16;
        int si = sidx[img];
        float ang = rot[si], sn, cs;
        sincosf(ang, &sn, &cs);
        float shx = shv[2 * si], shy = shv[2 * si + 1];
        float2 xv = ((const float2*)x)[p0 + li];
        float cx = fmaf(cs, xv.x, -sn * xv.y) + shx;
        float cy = fmaf(sn, xv.x,  cs * xv.y) + shy;

        // layer 1 -> split-f16 A fragments (feature = g*8 + 2d(+1) + 32s, same map as B)
        f16x8 Ah[4], Al[4];
        #pragma unroll
        for (int s = 0; s < 4; s++) {
            #pragma unroll
            for (int d = 0; d < 4; d++) {
                int fp = g * 4 + d + 16 * s;
                float4 wp = sW1[fp]; float2 bp = sB1[fp];
                float v0 = fmaxf(fmaf(cx, wp.x, fmaf(cy, wp.z, bp.x)), 0.f);
                float v1 = fmaxf(fmaf(cx, wp.y, fmaf(cy, wp.w, bp.y)), 0.f);
                _Float16 h0 = (_Float16)v0, h1 = (_Float16)v1;
                float r0 = v0 - (float)h0, r1 = v1 - (float)h1;
                Ah[s][2*d] = h0;            Ah[s][2*d+1] = h1;
                Al[s][2*d] = (_Float16)r0;  Al[s][2*d+1] = (_Float16)r1;
            }
        }

        // layer 2: 3-pass split-f16 MFMA, acc init = b2
        f32x4 acc[4];
        #pragma unroll
        for (int t = 0; t < 4; t++) {
            acc[t] = (f32x4){b2v[t], b2v[t], b2v[t], b2v[t]};
            #pragma unroll
            for (int s = 0; s < 4; s++) {
                acc[t] = __builtin_amdgcn_mfma_f32_16x16x32_f16(Ah[s], Bh[t][s], acc[t], 0, 0, 0);
                acc[t] = __builtin_amdgcn_mfma_f32_16x16x32_f16(Al[s], Bh[t][s], acc[t], 0, 0, 0);
                acc[t] = __builtin_amdgcn_mfma_f32_16x16x32_f16(Ah[s], Bl[t][s], acc[t], 0, 0, 0);
            }
        }

        // layer 3 partials: pixel row = g*4 + r, this lane's 4 cols
        float p3[4][3];
        #pragma unroll
        for (int r = 0; r < 4; r++) { p3[r][0] = 0.f; p3[r][1] = 0.f; p3[r][2] = 0.f; }
        #pragma unroll
        for (int t = 0; t < 4; t++)
            #pragma unroll
            for (int r = 0; r < 4; r++) {
                float v = fmaxf(acc[t][r], 0.f);
                p3[r][0] = fmaf(v, w3v[t][0], p3[r][0]);
                p3[r][1] = fmaf(v, w3v[t][1], p3[r][1]);
                p3[r][2] = fmaf(v, w3v[t][2], p3[r][2]);
            }
        // butterfly over the 16-lane (col) groups
        #pragma unroll
        for (int m = 1; m < 16; m <<= 1)
            #pragma unroll
            for (int r = 0; r < 4; r++) {
                p3[r][0] += __shfl_xor(p3[r][0], m, 64);
                p3[r][1] += __shfl_xor(p3[r][1], m, 64);
                p3[r][2] += __shfl_xor(p3[r][2], m, 64);
            }

        // cross col-half reduce via tiny LDS
        if (hf == 1 && li < 3) {
            #pragma unroll
            for (int r = 0; r < 4; r++) {
                float val = (li == 0) ? p3[r][0] : ((li == 1) ? p3[r][1] : p3[r][2]);
                sX[pset][g * 4 + r][li] = val;
            }
        }
        __syncthreads();
        if (hf == 0 && li < 3) {
            float b3v = b3g[li];
            float cwv = cw[si * 3 + li], cbv = cb[si * 3 + li];
            bool aff = (si != 0);
            float4 ov;
            #pragma unroll
            for (int r = 0; r < 4; r++) {
                float own = (li == 0) ? p3[r][0] : ((li == 1) ? p3[r][1] : p3[r][2]);
                float val = own + sX[pset][g * 4 + r][li] + b3v;
                if (aff) val = fmaf(val, cwv, cbv);
                ((float*)&ov)[r] = val;
            }
            *(float4*)(lr + li * NPIX_LR + p0 + g * 4) = ov;
        }
        __syncthreads();
    }
}

// ---------------- Kernel B: bilinear 2x upsample + variance MLP (fp32, pk-paired) ----------------
__global__ __launch_bounds__(256) void inr_upsample_var(
    const float* __restrict__ lr, const int* __restrict__ sidx,
    const float* __restrict__ shv, const float* __restrict__ vb2g,
    const char* __restrict__ ws_ro, float* __restrict__ out)
{
    __shared__ float4 s0[64], s1[64], s2[64];
    __shared__ float2 s3[64];
    int tid = threadIdx.x;
    if (tid < 64) {
        s0[tid] = ((const float4*)(ws_ro + WS_PK0))[tid];
        s1[tid] = ((const float4*)(ws_ro + WS_PK1))[tid];
        s2[tid] = ((const float4*)(ws_ro + WS_PK2))[tid];
        s3[tid] = ((const float2*)(ws_ro + WS_PK3))[tid];
    }
    __syncthreads();

    int p = blockIdx.x * 256 + tid;
    int b = p >> 18;
    int r = p & (OW * OW - 1);
    int oy = r >> 9, ox = r & (OW - 1);

    int my = oy >> 1; int y0, y1; float wy0, wy1;
    if (oy & 1) { y0 = my; y1 = my < 255 ? my + 1 : 255; wy0 = 0.75f; wy1 = 0.25f; }
    else        { y0 = my > 0 ? my - 1 : 0; y1 = my;     wy0 = 0.25f; wy1 = 0.75f; }
    int mx = ox >> 1; int x0, x1; float wx0, wx1;
    if (ox & 1) { x0 = mx; x1 = mx < 255 ? mx + 1 : 255; wx0 = 0.75f; wx1 = 0.25f; }
    else        { x0 = mx > 0 ? mx - 1 : 0; x1 = mx;     wx0 = 0.25f; wx1 = 0.75f; }

    int base = b * BQ;
    int i00 = base + y0 * 256 + x0, i01 = base + y0 * 256 + x1;
    int i10 = base + y1 * 256 + x0, i11 = base + y1 * 256 + x1;

    float o0, o1, o2;
    {
        const float* L0 = lr;
        const float* L1 = lr + NPIX_LR;
        const float* L2 = lr + 2 * NPIX_LR;
        o0 = wy0 * (wx0 * L0[i00] + wx1 * L0[i01]) + wy1 * (wx0 * L0[i10] + wx1 * L0[i11]);
        o1 = wy0 * (wx0 * L1[i00] + wx1 * L1[i01]) + wy1 * (wx0 * L1[i10] + wx1 * L1[i11]);
        o2 = wy0 * (wx0 * L2[i00] + wx1 * L2[i01]) + wy1 * (wx0 * L2[i10] + wx1 * L2[i11]);
    }
    out[p * 3 + 0] = o0; out[p * 3 + 1] = o1; out[p * 3 + 2] = o2;

    f32x2 O0 = {o0, o0}, O1 = {o1, o1}, O2 = {o2, o2};
    f32x2 a0 = {vb2g[0], 0.f}, a1 = {vb2g[1], 0.f}, a2 = {vb2g[2], 0.f};
    #pragma unroll 8
    for (int q = 0; q < 64; q++) {
        float4 w01 = s0[q], w2b = s1[q];
        f32x2 vh = pk_fma(O2, (f32x2){w2b.x, w2b.y}, (f32x2){w2b.z, w2b.w});
        vh = pk_fma(O1, (f32x2){w01.z, w01.w}, vh);
        vh = pk_fma(O0, (f32x2){w01.x, w01.y}, vh);
        vh = pk_max0(vh);
        float4 wc = s2[q]; float2 wc2 = s3[q];
        a0 = pk_fma(vh, (f32x2){wc.x, wc.y}, a0);
        a1 = pk_fma(vh, (f32x2){wc.z, wc.w}, a1);
        a2 = pk_fma(vh, (f32x2){wc2.x, wc2.y}, a2);
    }
    float* var = out + OUT_OFF_VAR;
    var[p * 3 + 0] = expf(a0[0] + a0[1]);
    var[p * 3 + 1] = expf(a1[0] + a1[1]);
    var[p * 3 + 2] = expf(a2[0] + a2[1]);

    if (p < 16) {
        int i = p & 7;
        int s2i = sidx[i];
        out[OUT_OFF_DX + p] = shv[2 * s2i + (p >> 3)];
    }
}

extern "C" void kernel_launch(void* const* d_in, const int* in_sizes, int n_in,
                              void* d_out, int out_size, void* d_ws, size_t ws_size,
                              hipStream_t stream)
{
    const float* x    = (const float*)d_in[0];
    const int*   sidx = (const int*)d_in[1];
    const float* shv  = (const float*)d_in[3];
    const float* rot  = (const float*)d_in[4];
    const float* cwp  = (const float*)d_in[5];
    const float* cbp  = (const float*)d_in[6];
    const float* w1   = (const float*)d_in[7];
    const float* b1   = (const float*)d_in[8];
    const float* w2   = (const float*)d_in[9];
    const float* b2   = (const float*)d_in[10];
    const float* w3   = (const float*)d_in[11];
    const float* b3   = (const float*)d_in[12];
    const float* vw1  = (const float*)d_in[13];
    const float* vb1  = (const float*)d_in[14];
    const float* vw2  = (const float*)d_in[15];
    const float* vb2  = (const float*)d_in[16];

    char* ws = (char*)d_ws;
    float* lr = (float*)(ws + WS_LR);

    inr_prep<<<33, 256, 0, stream>>>(w1, b1, w2, vw1, vb1, vw2, ws);
    inr_mlp_mfma<<<512, 256, 0, stream>>>(x, sidx, shv, rot, cwp, cbp,
                                          b2, w3, b3, ws, lr);
    inr_upsample_var<<<NPIX_HR / 256, 256, 0, stream>>>(lr, sidx, shv, vb2, ws,
                                                        (float*)d_out);
}

// Round 5
// 98.324 us; speedup vs baseline: 3.3545x; 1.6563x over previous
//
#include <hip/hip_runtime.h>
#include <math.h>

#define HID 128
#define BQ 65536
#define NPIX_LR 524288
#define OW 512
#define NPIX_HR 2097152
#define OUT_OFF_DX 6291456
#define OUT_OFF_VAR 6291472

// ws layout (bytes)
#define WS_A2   0        // 32768 : w2^T A-frags f16 (64 tiles: T = t2*8+kt)
#define WS_A1   32768    // 4096  : w1^T (+b1) A-frags (8 tiles, split-exact)
#define WS_A3   36864    // 4096  : w3^T A-frags (8 k-tiles)
#define WS_PK0  40960    // 1024  : vw1 rows0,1 pairs
#define WS_PK1  41984    // 1024  : vw1 row2 + vb1 pairs
#define WS_PK2  43008    // 1024  : vw2 c0,c1 pairs
#define WS_PK3  44032    // 512   : vw2 c2 pairs
#define WS_LR   45056    // 6291456 : low-res SoA f32

typedef __fp16   hf2   __attribute__((ext_vector_type(2)));
typedef _Float16 f16x4 __attribute__((ext_vector_type(4)));
typedef float    f32x4 __attribute__((ext_vector_type(4)));
typedef float    f32x2 __attribute__((ext_vector_type(2)));

static __device__ __host__ inline unsigned pack_f16pair(float a, float b) {
    hf2 h; h[0] = (__fp16)a; h[1] = (__fp16)b;
    return __builtin_bit_cast(unsigned, h);
}

static __device__ inline f32x2 pk_fma(f32x2 a, f32x2 b, f32x2 c) {
    f32x2 d;
    asm("v_pk_fma_f32 %0, %1, %2, %3" : "=v"(d) : "v"(a), "v"(b), "v"(c));
    return d;
}

// ---------------- Prep: pack weights into fragment / pair layouts ----------------
__device__ inline float a1val(int k, int m, const float* w1, const float* b1) {
    // k0..3: w1 hi (row k&1, duplicated for coord hi/lo); k4,5: w1 residual;
    // k8: b1 hi; k9: b1 residual; else 0
    if (k < 4) return w1[(k & 1) * HID + m];
    if (k < 6) { float v = w1[(k & 1) * HID + m]; return v - (float)(__fp16)v; }
    if (k == 8) return b1[m];
    if (k == 9) { float v = b1[m]; return v - (float)(__fp16)v; }
    return 0.f;
}

__global__ void inr_prep(const float* __restrict__ w1, const float* __restrict__ b1,
                         const float* __restrict__ w2, const float* __restrict__ w3,
                         const float* __restrict__ vw1, const float* __restrict__ vb1,
                         const float* __restrict__ vw2, char* ws)
{
    int tid = blockIdx.x * 256 + threadIdx.x;
    if (tid < 8192) {
        // w2^T A-frags: tile T=t2*8+kt: A[m=16t2+li][k=16kt+g*4+j] = w2[k][m]
        int d = tid & 1, l = (tid >> 1) & 63, T = tid >> 7;
        int g = l >> 4, li = l & 15, t2 = T >> 3, kt = T & 7;
        int k = 16 * kt + g * 4 + 2 * d, col = 16 * t2 + li;
        unsigned u = pack_f16pair(w2[k * HID + col], w2[(k + 1) * HID + col]);
        ((unsigned*)(ws + WS_A2))[((T >> 1) * 64 + l) * 4 + (T & 1) * 2 + d] = u;
    } else if (tid < 9216) {
        int q = tid - 8192;
        int d = q & 1, l = (q >> 1) & 63, t = q >> 7;
        int g = l >> 4, li = l & 15, m = 16 * t + li;
        int k0 = g * 4 + 2 * d;
        unsigned u = pack_f16pair(a1val(k0, m, w1, b1), a1val(k0 + 1, m, w1, b1));
        ((unsigned*)(ws + WS_A1))[((t >> 1) * 64 + l) * 4 + (t & 1) * 2 + d] = u;
    } else if (tid < 10240) {
        int q = tid - 9216;
        int d = q & 1, l = (q >> 1) & 63, kt = q >> 7;
        int g = l >> 4, li = l & 15;
        int c0 = 16 * kt + g * 4 + 2 * d;
        float v0 = (li < 3) ? w3[c0 * 3 + li] : 0.f;
        float v1 = (li < 3) ? w3[(c0 + 1) * 3 + li] : 0.f;
        ((unsigned*)(ws + WS_A3))[((kt >> 1) * 64 + l) * 4 + (kt & 1) * 2 + d] = pack_f16pair(v0, v1);
    } else if (tid < 10304) {
        int q = tid - 10240;   // hidden pair 0..63 for variance MLP
        float4 p0; p0.x = vw1[2*q]; p0.y = vw1[2*q+1]; p0.z = vw1[HID+2*q]; p0.w = vw1[HID+2*q+1];
        float4 p1; p1.x = vw1[2*HID+2*q]; p1.y = vw1[2*HID+2*q+1]; p1.z = vb1[2*q]; p1.w = vb1[2*q+1];
        float4 p2; p2.x = vw2[2*q*3+0]; p2.y = vw2[(2*q+1)*3+0]; p2.z = vw2[2*q*3+1]; p2.w = vw2[(2*q+1)*3+1];
        float2 p3; p3.x = vw2[2*q*3+2]; p3.y = vw2[(2*q+1)*3+2];
        ((float4*)(ws + WS_PK0))[q] = p0;
        ((float4*)(ws + WS_PK1))[q] = p1;
        ((float4*)(ws + WS_PK2))[q] = p2;
        ((float2*)(ws + WS_PK3))[q] = p3;
    }
}

// ---------------- Kernel A: all-MFMA MLP, one wave owns 16 px x 128 cols ----------------
__global__ __launch_bounds__(256, 2) void inr_mlp_mfma(
    const float* __restrict__ x, const int* __restrict__ sidx,
    const float* __restrict__ shv, const float* __restrict__ rot,
    const float* __restrict__ cw, const float* __restrict__ cb,
    const float* __restrict__ b2g, const float* __restrict__ b3g,
    const char* __restrict__ ws, float* __restrict__ lr)
{
    int tid = threadIdx.x, l = tid & 63, wv = tid >> 6;
    int li = l & 15, g = l >> 4;

    // stationary fragments (single copy, ~160 VGPR)
    f16x4 A2[64], A1[8], A3[8];
    const uint4* p2 = (const uint4*)(ws + WS_A2);
    #pragma unroll
    for (int i = 0; i < 32; i++) {
        uint4 u = p2[i * 64 + l];
        uint2 a = {u.x, u.y}, b = {u.z, u.w};
        A2[2*i]   = __builtin_bit_cast(f16x4, a);
        A2[2*i+1] = __builtin_bit_cast(f16x4, b);
    }
    const uint4* p1 = (const uint4*)(ws + WS_A1);
    #pragma unroll
    for (int i = 0; i < 4; i++) {
        uint4 u = p1[i * 64 + l];
        uint2 a = {u.x, u.y}, b = {u.z, u.w};
        A1[2*i]   = __builtin_bit_cast(f16x4, a);
        A1[2*i+1] = __builtin_bit_cast(f16x4, b);
    }
    const uint4* p3 = (const uint4*)(ws + WS_A3);
    #pragma unroll
    for (int i = 0; i < 4; i++) {
        uint4 u = p3[i * 64 + l];
        uint2 a = {u.x, u.y}, b = {u.z, u.w};
        A3[2*i]   = __builtin_bit_cast(f16x4, a);
        A3[2*i+1] = __builtin_bit_cast(f16x4, b);
    }

    int base = blockIdx.x * 1024;
    int img = base >> 16;
    int si = sidx[img];
    float ang = rot[si], sn, cs;
    sincosf(ang, &sn, &cs);
    float shx = shv[2*si], shy = shv[2*si+1];
    bool aff = (si != 0);
    float cw0 = cw[si*3+0], cw1 = cw[si*3+1], cw2 = cw[si*3+2];
    float cb0 = cb[si*3+0], cb1 = cb[si*3+1], cb2 = cb[si*3+2];
    float b30 = b3g[0], b31 = b3g[1], b32 = b3g[2];
    const unsigned ONES = 0x3C003C00u;  // (1.0h, 1.0h)

    #pragma unroll 1
    for (int it = 0; it < 16; ++it) {
        int p0 = base + it * 64 + wv * 16;
        float2 xv = ((const float2*)x)[p0 + li];
        float cx = fmaf(cs, xv.x, fmaf(-sn, xv.y, shx));
        float cy = fmaf(sn, xv.x, fmaf(cs, xv.y, shy));
        // split coords (exact layer-1 via K slots: g0:(cxh,cyh,cxl,cyl) g1:(cxh,cyh,0,0) g2:(1,1,0,0))
        hf2 ph = __builtin_amdgcn_cvt_pkrtz(cx, cy);
        float hx = (float)ph[0], hy = (float)ph[1];
        hf2 pl = __builtin_amdgcn_cvt_pkrtz(cx - hx, cy - hy);
        unsigned d0 = (g < 2) ? __builtin_bit_cast(unsigned, ph) : ((g == 2) ? ONES : 0u);
        unsigned d1 = (g == 0) ? __builtin_bit_cast(unsigned, pl) : 0u;
        uint2 b1u = {d0, d1};
        f16x4 B1 = __builtin_bit_cast(f16x4, b1u);

        // layer 1: 8 MFMAs, then relu+cvt in-lane (C-layout == next B-frag layout)
        f16x4 B2[8];
        #pragma unroll
        for (int t = 0; t < 8; t++) {
            f32x4 h = __builtin_amdgcn_mfma_f32_16x16x16f16(A1[t], B1, (f32x4){0.f,0.f,0.f,0.f}, 0, 0, 0);
            hf2 c01 = __builtin_amdgcn_cvt_pkrtz(fmaxf(h[0], 0.f), fmaxf(h[1], 0.f));
            hf2 c23 = __builtin_amdgcn_cvt_pkrtz(fmaxf(h[2], 0.f), fmaxf(h[3], 0.f));
            uint2 uu = {__builtin_bit_cast(unsigned, c01), __builtin_bit_cast(unsigned, c23)};
            B2[t] = __builtin_bit_cast(f16x4, uu);
        }

        // layer 2: 8 m-tiles x 8 k-tiles, acc init = b2 (f32 exact)
        f16x4 B3[8];
        #pragma unroll
        for (int t2 = 0; t2 < 8; t2++) {
            f32x4 c = *(const f32x4*)(b2g + 16 * t2 + g * 4);
            #pragma unroll
            for (int kt = 0; kt < 8; kt++)
                c = __builtin_amdgcn_mfma_f32_16x16x16f16(A2[t2 * 8 + kt], B2[kt], c, 0, 0, 0);
            hf2 c01 = __builtin_amdgcn_cvt_pkrtz(fmaxf(c[0], 0.f), fmaxf(c[1], 0.f));
            hf2 c23 = __builtin_amdgcn_cvt_pkrtz(fmaxf(c[2], 0.f), fmaxf(c[3], 0.f));
            uint2 uu = {__builtin_bit_cast(unsigned, c01), __builtin_bit_cast(unsigned, c23)};
            B3[t2] = __builtin_bit_cast(f16x4, uu);
        }

        // layer 3: 8 k-tiles into 2 parallel chains
        f32x4 acc3a = {0.f,0.f,0.f,0.f}, acc3b = {0.f,0.f,0.f,0.f};
        #pragma unroll
        for (int k3 = 0; k3 < 8; k3 += 2) {
            acc3a = __builtin_amdgcn_mfma_f32_16x16x16f16(A3[k3],     B3[k3],     acc3a, 0, 0, 0);
            acc3b = __builtin_amdgcn_mfma_f32_16x16x16f16(A3[k3 + 1], B3[k3 + 1], acc3b, 0, 0, 0);
        }

        if (g == 0) {   // rows 0..2 = channels, col = px = li
            float v0 = acc3a[0] + acc3b[0] + b30;
            float v1 = acc3a[1] + acc3b[1] + b31;
            float v2 = acc3a[2] + acc3b[2] + b32;
            if (aff) {
                v0 = fmaf(v0, cw0, cb0);
                v1 = fmaf(v1, cw1, cb1);
                v2 = fmaf(v2, cw2, cb2);
            }
            lr[p0 + li] = v0;
            lr[NPIX_LR + p0 + li] = v1;
            lr[2 * NPIX_LR + p0 + li] = v2;
        }
    }
}

// ---------------- Kernel B: 4x2 quad/thread bilinear + variance MLP ----------------
__global__ __launch_bounds__(256, 3) void inr_upsample_var(
    const float* __restrict__ lr, const int* __restrict__ sidx,
    const float* __restrict__ shv, const float* __restrict__ vb2g,
    const char* __restrict__ ws, float* __restrict__ out)
{
    __shared__ float4 s0[64], s1[64], s2[64];
    __shared__ float2 s3[64];
    int tid = threadIdx.x;
    if (tid < 64) {
        s0[tid] = ((const float4*)(ws + WS_PK0))[tid];
        s1[tid] = ((const float4*)(ws + WS_PK1))[tid];
        s2[tid] = ((const float4*)(ws + WS_PK2))[tid];
        s3[tid] = ((const float2*)(ws + WS_PK3))[tid];
    }
    __syncthreads();

    int t = blockIdx.x * 256 + tid;      // 0..262143, 8 px each (4 cols x 2 rows)
    int b = t >> 15, r = t & 32767;
    int ty = r >> 7, tx = r & 127;
    int ry0 = ty > 0 ? ty - 1 : 0, ry1 = ty, ry2 = ty < 255 ? ty + 1 : 255;
    int c0 = tx > 0 ? 2 * tx - 1 : 0, c1 = 2 * tx, c2 = 2 * tx + 1, c3 = tx < 127 ? 2 * tx + 2 : 255;
    int base = b << 16;

    f32x2 o2[2][4][3];
    #pragma unroll
    for (int ch = 0; ch < 3; ch++) {
        const float* L = lr + ch * NPIX_LR + base;
        float h[3][4];
        #pragma unroll
        for (int rr = 0; rr < 3; rr++) {
            int ro = (rr == 0 ? ry0 : (rr == 1 ? ry1 : ry2)) * 256;
            float a = L[ro + c0], bb = L[ro + c1], cc = L[ro + c2], dd = L[ro + c3];
            h[rr][0] = 0.25f * a  + 0.75f * bb;
            h[rr][1] = 0.75f * bb + 0.25f * cc;
            h[rr][2] = 0.25f * bb + 0.75f * cc;
            h[rr][3] = 0.75f * cc + 0.25f * dd;
        }
        #pragma unroll
        for (int xi = 0; xi < 4; xi++) {
            float e = 0.25f * h[0][xi] + 0.75f * h[1][xi];
            float o = 0.75f * h[1][xi] + 0.25f * h[2][xi];
            o2[0][xi][ch][0] = e; o2[0][xi][ch][1] = e;
            o2[1][xi][ch][0] = o; o2[1][xi][ch][1] = o;
        }
    }

    int prow = (b << 18) + (2 * ty) * 512 + 4 * tx;   // p%4==0 -> 16B aligned stores
    #pragma unroll
    for (int rr = 0; rr < 2; rr++) {
        float* dst = out + (size_t)(prow + rr * 512) * 3;
        float4 f0 = {o2[rr][0][0][0], o2[rr][0][1][0], o2[rr][0][2][0], o2[rr][1][0][0]};
        float4 f1 = {o2[rr][1][1][0], o2[rr][1][2][0], o2[rr][2][0][0], o2[rr][2][1][0]};
        float4 f2 = {o2[rr][2][2][0], o2[rr][3][0][0], o2[rr][3][1][0], o2[rr][3][2][0]};
        ((float4*)dst)[0] = f0; ((float4*)dst)[1] = f1; ((float4*)dst)[2] = f2;
    }

    // variance MLP: 3 -> 128 -> 3 over 8 px, pk-paired hidden units
    float vb20 = vb2g[0], vb21 = vb2g[1], vb22 = vb2g[2];
    f32x2 a[8][3];
    #pragma unroll
    for (int px = 0; px < 8; px++) {
        a[px][0] = (f32x2){vb20, 0.f};
        a[px][1] = (f32x2){vb21, 0.f};
        a[px][2] = (f32x2){vb22, 0.f};
    }
    #pragma unroll 2
    for (int q = 0; q < 64; q++) {
        float4 w01 = s0[q], w2b = s1[q], wc01 = s2[q];
        float2 wc2 = s3[q];
        f32x2 W0 = {w01.x, w01.y}, W1 = {w01.z, w01.w};
        f32x2 W2 = {w2b.x, w2b.y}, Bp = {w2b.z, w2b.w};
        f32x2 C0 = {wc01.x, wc01.y}, C1 = {wc01.z, wc01.w}, C2 = {wc2.x, wc2.y};
        #pragma unroll
        for (int px = 0; px < 8; px++) {
            int rr = px >> 2, xi = px & 3;
            f32x2 vh = pk_fma(o2[rr][xi][2], W2, Bp);
            vh = pk_fma(o2[rr][xi][1], W1, vh);
            vh = pk_fma(o2[rr][xi][0], W0, vh);
            vh[0] = fmaxf(vh[0], 0.f); vh[1] = fmaxf(vh[1], 0.f);
            a[px][0] = pk_fma(vh, C0, a[px][0]);
            a[px][1] = pk_fma(vh, C1, a[px][1]);
            a[px][2] = pk_fma(vh, C2, a[px][2]);
        }
    }
    float* var = out + OUT_OFF_VAR;
    #pragma unroll
    for (int rr = 0; rr < 2; rr++) {
        float* dst = var + (size_t)(prow + rr * 512) * 3;
        float v[12];
        #pragma unroll
        for (int xi = 0; xi < 4; xi++)
            #pragma unroll
            for (int ch = 0; ch < 3; ch++)
                v[xi * 3 + ch] = expf(a[rr * 4 + xi][ch][0] + a[rr * 4 + xi][ch][1]);
        float4 f0 = {v[0], v[1], v[2], v[3]};
        float4 f1 = {v[4], v[5], v[6], v[7]};
        float4 f2 = {v[8], v[9], v[10], v[11]};
        ((float4*)dst)[0] = f0; ((float4*)dst)[1] = f1; ((float4*)dst)[2] = f2;
    }

    if (t < 16) {
        int i = t & 7;
        out[OUT_OFF_DX + t] = shv[2 * sidx[i] + (t >> 3)];
    }
}

extern "C" void kernel_launch(void* const* d_in, const int* in_sizes, int n_in,
                              void* d_out, int out_size, void* d_ws, size_t ws_size,
                              hipStream_t stream)
{
    const float* x    = (const float*)d_in[0];
    const int*   sidx = (const int*)d_in[1];
    const float* shv  = (const float*)d_in[3];
    const float* rot  = (const float*)d_in[4];
    const float* cwp  = (const float*)d_in[5];
    const float* cbp  = (const float*)d_in[6];
    const float* w1   = (const float*)d_in[7];
    const float* b1   = (const float*)d_in[8];
    const float* w2   = (const float*)d_in[9];
    const float* b2   = (const float*)d_in[10];
    const float* w3   = (const float*)d_in[11];
    const float* b3   = (const float*)d_in[12];
    const float* vw1  = (const float*)d_in[13];
    const float* vb1  = (const float*)d_in[14];
    const float* vw2  = (const float*)d_in[15];
    const float* vb2  = (const float*)d_in[16];

    char* ws = (char*)d_ws;
    float* lr = (float*)(ws + WS_LR);

    inr_prep<<<41, 256, 0, stream>>>(w1, b1, w2, w3, vw1, vb1, vw2, ws);
    inr_mlp_mfma<<<512, 256, 0, stream>>>(x, sidx, shv, rot, cwp, cbp, b2, b3, ws, lr);
    inr_upsample_var<<<1024, 256, 0, stream>>>(lr, sidx, shv, vb2, ws, (float*)d_out);
}